// Round 1
// baseline (334.699 us; speedup 1.0000x reference)
//
#include <hip/hip_runtime.h>
#include <math.h>

#define Bx 16
#define Cx 64
#define Hx 128
#define Wx 128

#define TW 32
#define TH 8
#define CCH 8
#define HALO_W (TW + 2)
#define HALO_H (TH + 2)
#define CHUNK_ELEMS (CCH * HALO_H * HALO_W)   // 8*10*34 = 2720

__global__ __launch_bounds__(256, 2)
void da_conv_main(const float* __restrict__ x0,
                  const float* __restrict__ x_deg,
                  const float* __restrict__ kw1,
                  const float* __restrict__ kw2,
                  const float* __restrict__ convw,
                  const float* __restrict__ convb,
                  const float* __restrict__ ca_w1,
                  const float* __restrict__ ca_w2,
                  const float* __restrict__ g1w,
                  const float* __restrict__ g1b,
                  const float* __restrict__ g2w,
                  const float* __restrict__ g2b,
                  float* __restrict__ out)
{
    const int b  = blockIdx.z;
    const int h0 = blockIdx.y * TH;
    const int w0 = blockIdx.x * TW;
    const int tid = threadIdx.x;
    const int tx = tid & (TW - 1);
    const int ty = tid >> 5;

    __shared__ float sx[CHUNK_ELEMS];     // x0 chunk with halo
    __shared__ float skern[Cx * 9 * 4];   // [c][k][r]  (r fastest -> no bank conflict)
    __shared__ float satt[Cx * 4];        // [c][r]
    __shared__ float h1[16];
    __shared__ float a1[16];

    // ---- hypernetwork (tiny, recomputed per block) ----
    if (tid < 32) {
        const int j = tid & 15;
        const float* wsrc = (tid < 16) ? (kw1 + j * Cx) : (ca_w1 + j * Cx);
        float acc = 0.f;
        #pragma unroll 8
        for (int c = 0; c < Cx; ++c) acc = fmaf(x_deg[b * Cx + c], wsrc[c], acc);
        acc = acc > 0.f ? acc : 0.1f * acc;          // leaky_relu 0.1
        if (tid < 16) h1[j] = acc; else a1[j] = acc;
    }
    __syncthreads();

    // kern[b,g,o] = sum_i h1[b,g,i] * kw2[g,o,i];  o = c*9+k ; store [c][k][g]
    for (int o4 = tid; o4 < 4 * 576; o4 += 256) {
        const int g = o4 / 576;
        const int o = o4 - g * 576;
        float acc = 0.f;
        #pragma unroll
        for (int i = 0; i < 4; ++i)
            acc = fmaf(h1[g * 4 + i], kw2[(g * 576 + o) * 4 + i], acc);
        const int c = o / 9;
        const int k = o - c * 9;
        skern[c * 36 + k * 4 + g] = acc;
    }
    // att[b,r,c] = sigmoid(sum_i a1[b,r,i] * ca_w2[r,c,i]); store [c][r]
    {
        const int r = tid >> 6;
        const int c = tid & 63;
        float acc = 0.f;
        #pragma unroll
        for (int i = 0; i < 4; ++i)
            acc = fmaf(a1[r * 4 + i], ca_w2[(r * Cx + c) * 4 + i], acc);
        satt[c * 4 + r] = 1.f / (1.f + expf(-acc));
    }

    const float* xb = x0 + (size_t)b * Cx * Hx * Wx;

    // ---- pass 1: guide convs -> argmax r1, r2 ----
    float ga[8];
    #pragma unroll
    for (int r = 0; r < 4; ++r) { ga[r] = g1b[r]; ga[4 + r] = g2b[r]; }

    for (int ch = 0; ch < Cx / CCH; ++ch) {
        __syncthreads();
        for (int e = tid; e < CHUNK_ELEMS; e += 256) {
            const int cc  = e / (HALO_H * HALO_W);
            const int rem = e - cc * (HALO_H * HALO_W);
            const int row = rem / HALO_W;
            const int col = rem - row * HALO_W;
            const int gh = h0 - 1 + row;
            const int gw = w0 - 1 + col;
            float v = 0.f;
            if ((unsigned)gh < Hx && (unsigned)gw < Wx)
                v = xb[(size_t)(ch * CCH + cc) * Hx * Wx + gh * Wx + gw];
            sx[e] = v;
        }
        __syncthreads();

        float pg[8] = {0.f, 0.f, 0.f, 0.f, 0.f, 0.f, 0.f, 0.f};
        #pragma unroll
        for (int cc = 0; cc < CCH; ++cc) {
            const int c = ch * CCH + cc;
            float n[9];
            #pragma unroll
            for (int kh = 0; kh < 3; ++kh)
                #pragma unroll
                for (int kw = 0; kw < 3; ++kw)
                    n[kh * 3 + kw] = sx[cc * (HALO_H * HALO_W) + (ty + kh) * HALO_W + (tx + kw)];
            #pragma unroll
            for (int r = 0; r < 4; ++r) {
                const float* wp1 = g1w + (r * Cx + c) * 9;   // uniform -> scalar loads
                const float* wp2 = g2w + (r * Cx + c) * 9;
                float s1 = 0.f, s2 = 0.f;
                #pragma unroll
                for (int k = 0; k < 9; ++k) {
                    s1 = fmaf(n[k], wp1[k], s1);
                    s2 = fmaf(n[k], wp2[k], s2);
                }
                pg[r]     += s1;
                pg[4 + r] += s2;
            }
        }
        #pragma unroll
        for (int i = 0; i < 8; ++i) ga[i] += pg[i];   // chunked accumulation (less drift)
    }

    int r1 = 0, r2 = 0;
    {
        float m = ga[0];
        #pragma unroll
        for (int r = 1; r < 4; ++r) if (ga[r] > m) { m = ga[r]; r1 = r; }     // first-max ties
        float m2 = ga[4];
        #pragma unroll
        for (int r = 1; r < 4; ++r) if (ga[4 + r] > m2) { m2 = ga[4 + r]; r2 = r; }
    }

    // ---- pass 2: routed depthwise conv + 1x1 conv accumulate ----
    float y[Cx];
    #pragma unroll
    for (int o = 0; o < Cx; ++o) y[o] = 0.f;

    for (int ch = 0; ch < Cx / CCH; ++ch) {
        __syncthreads();
        for (int e = tid; e < CHUNK_ELEMS; e += 256) {
            const int cc  = e / (HALO_H * HALO_W);
            const int rem = e - cc * (HALO_H * HALO_W);
            const int row = rem / HALO_W;
            const int col = rem - row * HALO_W;
            const int gh = h0 - 1 + row;
            const int gw = w0 - 1 + col;
            float v = 0.f;
            if ((unsigned)gh < Hx && (unsigned)gw < Wx)
                v = xb[(size_t)(ch * CCH + cc) * Hx * Wx + gh * Wx + gw];
            sx[e] = v;
        }
        __syncthreads();

        #pragma unroll
        for (int cc = 0; cc < CCH; ++cc) {
            const int c = ch * CCH + cc;
            float n[9];
            #pragma unroll
            for (int kh = 0; kh < 3; ++kh)
                #pragma unroll
                for (int kw = 0; kw < 3; ++kw)
                    n[kh * 3 + kw] = sx[cc * (HALO_H * HALO_W) + (ty + kh) * HALO_W + (tx + kw)];

            float dw = 0.f;
            #pragma unroll
            for (int k = 0; k < 9; ++k)
                dw = fmaf(n[k], skern[c * 36 + k * 4 + r1], dw);
            const float routed = dw > 0.f ? dw : 0.1f * dw;

            const float* cw = convw + c;                 // convw[o*64+c], uniform per o
            #pragma unroll
            for (int o = 0; o < Cx; ++o)
                y[o] = fmaf(cw[o * Cx], routed, y[o]);
        }
    }

    // ---- epilogue: bias + CA branch + store ----
    const int hh = h0 + ty;
    const int ww = w0 + tx;
    float* op = out + (size_t)b * Cx * Hx * Wx + hh * Wx + ww;
    const float* xp = xb + hh * Wx + ww;
    #pragma unroll
    for (int o = 0; o < Cx; ++o) {
        const float v = y[o] + convb[o] + xp[(size_t)o * Hx * Wx] * satt[o * 4 + r2];
        op[(size_t)o * Hx * Wx] = v;
    }
}

extern "C" void kernel_launch(void* const* d_in, const int* in_sizes, int n_in,
                              void* d_out, int out_size, void* d_ws, size_t ws_size,
                              hipStream_t stream) {
    const float* x0     = (const float*)d_in[0];
    const float* x_deg  = (const float*)d_in[1];
    const float* kw1    = (const float*)d_in[2];
    const float* kw2    = (const float*)d_in[3];
    const float* convw  = (const float*)d_in[4];
    const float* convb  = (const float*)d_in[5];
    const float* ca_w1  = (const float*)d_in[6];
    const float* ca_w2  = (const float*)d_in[7];
    const float* g1w    = (const float*)d_in[8];
    const float* g1b    = (const float*)d_in[9];
    const float* g2w    = (const float*)d_in[10];
    const float* g2b    = (const float*)d_in[11];
    float* outp = (float*)d_out;

    dim3 grid(Wx / TW, Hx / TH, Bx);   // 4 x 16 x 16 = 1024 blocks
    da_conv_main<<<grid, 256, 0, stream>>>(x0, x_deg, kw1, kw2, convw, convb,
                                           ca_w1, ca_w2, g1w, g1b, g2w, g2b, outp);
}